// Round 2
// baseline (523.632 us; speedup 1.0000x reference)
//
#include <hip/hip_runtime.h>
#include <hip/hip_bf16.h>

#define ED 256   // embed dim
#define NW 8     // num weights
#define NR 5     // num relations
#define BM 64    // rows per block

typedef float   f32x4  __attribute__((ext_vector_type(4)));
typedef __bf16  bf16x8 __attribute__((ext_vector_type(8)));
typedef short   short8v __attribute__((ext_vector_type(8)));

__device__ __forceinline__ unsigned short f2bf(float f) {
    return __builtin_bit_cast(unsigned short, __float2bfloat16(f));
}

// ---------------------------------------------------------------------------
// Prep: S_T[r][j][i] = sum_w ws[w,r] * rel[w, i*ED + j]   (bf16, transposed)
// ---------------------------------------------------------------------------
__global__ void prep_S(const float* __restrict__ rel,
                       const float* __restrict__ ws,
                       unsigned short* __restrict__ S_T) {
    int idx = blockIdx.x * blockDim.x + threadIdx.x;
    if (idx >= ED * ED) return;
    int i = idx & (ED - 1);
    int j = idx >> 8;
    float acc[NR];
#pragma unroll
    for (int r = 0; r < NR; ++r) acc[r] = 0.f;
#pragma unroll
    for (int w = 0; w < NW; ++w) {
        float rv = rel[(size_t)w * ED * ED + (size_t)i * ED + j];
#pragma unroll
        for (int r = 0; r < NR; ++r) acc[r] += rv * ws[w * NR + r];
    }
#pragma unroll
    for (int r = 0; r < NR; ++r)
        S_T[((size_t)r * ED + j) * ED + i] = f2bf(acc[r]);
}

// ---------------------------------------------------------------------------
// Main kernel. Per block: 64 batch rows, 4 waves each owning a 64-col slab.
// For each r: acc = e1_tile @ S_r (MFMA), fused epilogue multiplies by e2
// (hoisted in registers, packed bf16) and reduces. One __syncthreads total
// after staging, one before the final cross-wave reduce.
// ---------------------------------------------------------------------------
__global__ __launch_bounds__(256, 3) void bilinear_kernel(
    const float* __restrict__ e1, const float* __restrict__ e2,
    const unsigned short* __restrict__ S_T, float* __restrict__ out) {

    __shared__ __align__(16) unsigned short Alds[BM * ED];  // 32 KB swizzled bf16
    __shared__ float Red[BM][NR][4];                        // 5 KB partials

    const int t = threadIdx.x;
    const long b0 = (long)blockIdx.x * BM;
    const int wave = t >> 6;
    const int lane = t & 63;
    const int l15  = lane & 15;
    const int l4   = lane >> 4;

    // ---- stage e1 tile: f32 -> bf16, XOR swizzle (elem ^= (row&7)<<3) ----
#pragma unroll
    for (int u = 0; u < 16; ++u) {
        int idx = u * 256 + t;
        int row = idx >> 6;
        int c4  = idx & 63;
        const float4 v = *(const float4*)(e1 + (b0 + row) * ED + c4 * 4);
        ushort4 p = make_ushort4(f2bf(v.x), f2bf(v.y), f2bf(v.z), f2bf(v.w));
        *(ushort4*)(&Alds[row * ED + ((c4 * 4) ^ ((row & 7) << 3))]) = p;
    }

    // ---- hoist e2 (r-invariant) into packed bf16 registers: 32 VGPRs ----
    // e2p[m*4+reg][h] packs cols {wave*64 + (2h)*16 + l15, wave*64 + (2h+1)*16 + l15}
    unsigned int e2p[16][2];
#pragma unroll
    for (int m = 0; m < 4; ++m)
#pragma unroll
        for (int reg = 0; reg < 4; ++reg) {
            const float* erow =
                e2 + (b0 + m * 16 + l4 * 4 + reg) * ED + wave * 64 + l15;
#pragma unroll
            for (int h = 0; h < 2; ++h) {
                float a = erow[(2 * h) * 16];
                float b = erow[(2 * h + 1) * 16];
                e2p[m * 4 + reg][h] =
                    (unsigned)f2bf(a) | ((unsigned)f2bf(b) << 16);
            }
        }

    __syncthreads();

    // this wave's column slab of S_T for r=0; element (r,n,kb):
    //   Sw + r*ED*ED + (n*16+l15)*ED + kb*32 + l4*8
    const unsigned short* Sw = S_T + (size_t)(wave * 64) * ED;

    // ---- register double-buffer for B fragments ----
    short8v bvb[2][4];
#pragma unroll
    for (int n = 0; n < 4; ++n)
        bvb[0][n] = *(const short8v*)(Sw + (size_t)(n * 16 + l15) * ED + l4 * 8);

    for (int r = 0; r < NR; ++r) {
        f32x4 acc[4][4];
#pragma unroll
        for (int m = 0; m < 4; ++m)
#pragma unroll
            for (int n = 0; n < 4; ++n)
                acc[m][n] = f32x4{0.f, 0.f, 0.f, 0.f};

#pragma unroll
        for (int kb = 0; kb < 8; ++kb) {
            const int cur = kb & 1;

            // prefetch next (r,kb) B fragments — one iteration ahead
            if (kb < 7) {
                const unsigned short* p =
                    Sw + (size_t)r * ED * ED + (kb + 1) * 32 + l4 * 8;
#pragma unroll
                for (int n = 0; n < 4; ++n)
                    bvb[cur ^ 1][n] =
                        *(const short8v*)(p + (size_t)(n * 16 + l15) * ED);
            } else if (r < NR - 1) {
                const unsigned short* p =
                    Sw + (size_t)(r + 1) * ED * ED + l4 * 8;
#pragma unroll
                for (int n = 0; n < 4; ++n)
                    bvb[cur ^ 1][n] =
                        *(const short8v*)(p + (size_t)(n * 16 + l15) * ED);
            }

            // A fragments from LDS (swizzled)
            const int kofs = kb * 32 + l4 * 8;
            bf16x8 av[4];
#pragma unroll
            for (int m = 0; m < 4; ++m) {
                int row = m * 16 + l15;
                av[m] = __builtin_bit_cast(bf16x8,
                    *(const short8v*)(&Alds[row * ED + (kofs ^ ((row & 7) << 3))]));
            }

#pragma unroll
            for (int m = 0; m < 4; ++m)
#pragma unroll
                for (int n = 0; n < 4; ++n)
                    acc[m][n] = __builtin_amdgcn_mfma_f32_16x16x32_bf16(
                        av[m], __builtin_bit_cast(bf16x8, bvb[cur][n]),
                        acc[m][n], 0, 0, 0);
        }

        // ---- fused epilogue: multiply by e2 (regs), reduce over 16 lanes ----
        // C frag: row = m*16 + l4*4 + reg, col = wave*64 + n*16 + l15
#pragma unroll
        for (int m = 0; m < 4; ++m)
#pragma unroll
            for (int reg = 0; reg < 4; ++reg) {
                float p = 0.f;
#pragma unroll
                for (int n = 0; n < 4; ++n) {
                    unsigned u = e2p[m * 4 + reg][n >> 1];
                    unsigned bits = (n & 1) ? (u & 0xffff0000u) : (u << 16);
                    p += acc[m][n][reg] * __builtin_bit_cast(float, bits);
                }
#pragma unroll
                for (int off = 1; off < 16; off <<= 1)
                    p += __shfl_xor(p, off);
                if (l15 == 0)
                    Red[m * 16 + l4 * 4 + reg][r][wave] = p;
            }
    }

    __syncthreads();
    if (t < BM) {
#pragma unroll
        for (int r = 0; r < NR; ++r)
            out[(b0 + t) * NR + r] =
                Red[t][r][0] + Red[t][r][1] + Red[t][r][2] + Red[t][r][3];
    }
}

extern "C" void kernel_launch(void* const* d_in, const int* in_sizes, int n_in,
                              void* d_out, int out_size, void* d_ws, size_t ws_size,
                              hipStream_t stream) {
    const float* e1  = (const float*)d_in[0];
    const float* e2  = (const float*)d_in[1];
    const float* rel = (const float*)d_in[2];
    const float* ws  = (const float*)d_in[3];
    float* out = (float*)d_out;
    unsigned short* S_T = (unsigned short*)d_ws;  // NR*ED*ED bf16 = 640 KB

    prep_S<<<(ED * ED + 255) / 256, 256, 0, stream>>>(rel, ws, S_T);

    int B = in_sizes[0] / ED;          // 131072
    int grid = B / BM;                 // 2048
    bilinear_kernel<<<grid, 256, 0, stream>>>(e1, e2, S_T, out);
}

// Round 3
// 455.762 us; speedup vs baseline: 1.1489x; 1.1489x over previous
//
#include <hip/hip_runtime.h>
#include <hip/hip_bf16.h>

#define ED 256   // embed dim
#define NW 8     // num weights
#define NR 5     // num relations
#define BM 64    // rows per block

typedef float   f32x4   __attribute__((ext_vector_type(4)));
typedef float   f32x4v  __attribute__((ext_vector_type(4)));
typedef __bf16  bf16x8  __attribute__((ext_vector_type(8)));
typedef short   short8v __attribute__((ext_vector_type(8)));

__device__ __forceinline__ unsigned short f2bf(float f) {
    return __builtin_bit_cast(unsigned short, __float2bfloat16(f));
}

// ---------------------------------------------------------------------------
// Prep: S_T[r][j][i] = sum_w ws[w,r] * rel[w, i*ED + j]   (bf16, transposed)
// ---------------------------------------------------------------------------
__global__ void prep_S(const float* __restrict__ rel,
                       const float* __restrict__ ws,
                       unsigned short* __restrict__ S_T) {
    int idx = blockIdx.x * blockDim.x + threadIdx.x;
    if (idx >= ED * ED) return;
    int i = idx & (ED - 1);
    int j = idx >> 8;
    float acc[NR];
#pragma unroll
    for (int r = 0; r < NR; ++r) acc[r] = 0.f;
#pragma unroll
    for (int w = 0; w < NW; ++w) {
        float rv = rel[(size_t)w * ED * ED + (size_t)i * ED + j];
#pragma unroll
        for (int r = 0; r < NR; ++r) acc[r] += rv * ws[w * NR + r];
    }
#pragma unroll
    for (int r = 0; r < NR; ++r)
        S_T[((size_t)r * ED + j) * ED + i] = f2bf(acc[r]);
}

// ---------------------------------------------------------------------------
// Main kernel: 512 threads = 8 waves. Wave (mh, ws): mh = row-half (32 rows),
// ws = 64-col slab of S. acc[2][4] (32 AGPR) keeps total regs ~108 so
// 4 waves/SIMD (16 waves/CU) are resident. e1/e2 loaded nontemporally so the
// shared 640 KB S_T stays L2-resident. B-frags (S_T) prefetched 1 step ahead
// over the flattened (r,kb) sequence.
// ---------------------------------------------------------------------------
__global__ __launch_bounds__(512, 4) void bilinear_kernel(
    const float* __restrict__ e1, const float* __restrict__ e2,
    const unsigned short* __restrict__ S_T, float* __restrict__ out) {

    __shared__ __align__(16) unsigned short Alds[BM * ED];  // 32 KB swizzled bf16
    __shared__ float Red[BM][NR][4];                        // 5 KB partials

    const int t = threadIdx.x;
    const long b0 = (long)blockIdx.x * BM;
    const int wave = t >> 6;
    const int lane = t & 63;
    const int l15  = lane & 15;
    const int l4   = lane >> 4;
    const int mh   = wave >> 2;   // row half: rows [mh*32, mh*32+32)
    const int ws   = wave & 3;    // col slab:  cols [ws*64, ws*64+64)

    // ---- stage e1 tile: nontemporal f32 -> bf16, XOR swizzle ----
#pragma unroll
    for (int u = 0; u < 8; ++u) {
        int idx = u * 512 + t;          // float4 index; 64 float4 per row
        int row = idx >> 6;
        int c4  = idx & 63;
        f32x4v v = __builtin_nontemporal_load(
            (const f32x4v*)(e1 + (b0 + row) * ED + c4 * 4));
        ushort4 p = make_ushort4(f2bf(v[0]), f2bf(v[1]), f2bf(v[2]), f2bf(v[3]));
        *(ushort4*)(&Alds[row * ED + ((c4 * 4) ^ ((row & 7) << 3))]) = p;
    }

    // ---- hoist e2 (r-invariant) into packed bf16 regs: 16 VGPRs/thread ----
    // e2p[m*4+reg][h] packs cols {ws*64+(2h)*16+l15, ws*64+(2h+1)*16+l15}
    unsigned int e2p[8][2];
#pragma unroll
    for (int m = 0; m < 2; ++m)
#pragma unroll
        for (int reg = 0; reg < 4; ++reg) {
            const float* erow =
                e2 + (b0 + mh * 32 + m * 16 + l4 * 4 + reg) * ED + ws * 64 + l15;
#pragma unroll
            for (int h = 0; h < 2; ++h) {
                float a = __builtin_nontemporal_load(erow + (2 * h) * 16);
                float b = __builtin_nontemporal_load(erow + (2 * h + 1) * 16);
                e2p[m * 4 + reg][h] =
                    (unsigned)f2bf(a) | ((unsigned)f2bf(b) << 16);
            }
        }

    __syncthreads();

    // B-frag addressing: row (r*256 + ws*64 + n*16 + l15), k = kb*32 + l4*8
    const size_t nstride = (size_t)16 * ED;                     // shorts
    const unsigned short* Sbase =
        S_T + (size_t)(ws * 64 + l15) * ED + l4 * 8;

    // ---- 1-ahead register ring for B fragments, flattened s = r*8 + kb ----
    short8v bvb[2][4];
#pragma unroll
    for (int n = 0; n < 4; ++n)
        bvb[0][n] = *(const short8v*)(Sbase + n * nstride);     // s = 0

    for (int r = 0; r < NR; ++r) {
        f32x4 acc[2][4];
#pragma unroll
        for (int m = 0; m < 2; ++m)
#pragma unroll
            for (int n = 0; n < 4; ++n)
                acc[m][n] = f32x4{0.f, 0.f, 0.f, 0.f};

#pragma unroll
        for (int kb = 0; kb < 8; ++kb) {
            const int s   = r * 8 + kb;
            const int cur = s & 1;

            if (s + 1 < NR * 8) {
                const int rn = (s + 1) >> 3;
                const int kn = (s + 1) & 7;
                const unsigned short* p =
                    Sbase + (size_t)rn * ED * ED + kn * 32;
#pragma unroll
                for (int n = 0; n < 4; ++n)
                    bvb[cur ^ 1][n] = *(const short8v*)(p + n * nstride);
            }

            // A fragments from LDS (swizzled)
            const int kofs = kb * 32 + l4 * 8;
            bf16x8 av[2];
#pragma unroll
            for (int m = 0; m < 2; ++m) {
                int row = mh * 32 + m * 16 + l15;
                av[m] = __builtin_bit_cast(bf16x8,
                    *(const short8v*)(&Alds[row * ED + (kofs ^ ((row & 7) << 3))]));
            }

#pragma unroll
            for (int m = 0; m < 2; ++m)
#pragma unroll
                for (int n = 0; n < 4; ++n)
                    acc[m][n] = __builtin_amdgcn_mfma_f32_16x16x32_bf16(
                        av[m], __builtin_bit_cast(bf16x8, bvb[cur][n]),
                        acc[m][n], 0, 0, 0);
        }

        // ---- fused epilogue: multiply by e2 (regs), 16-lane reduce ----
        // C frag: row = mh*32 + m*16 + l4*4 + reg, col = ws*64 + n*16 + l15
#pragma unroll
        for (int m = 0; m < 2; ++m)
#pragma unroll
            for (int reg = 0; reg < 4; ++reg) {
                float p = 0.f;
#pragma unroll
                for (int n = 0; n < 4; ++n) {
                    unsigned u = e2p[m * 4 + reg][n >> 1];
                    unsigned bits = (n & 1) ? (u & 0xffff0000u) : (u << 16);
                    p += acc[m][n][reg] * __builtin_bit_cast(float, bits);
                }
#pragma unroll
                for (int off = 1; off < 16; off <<= 1)
                    p += __shfl_xor(p, off);
                if (l15 == 0)
                    Red[mh * 32 + m * 16 + l4 * 4 + reg][r][ws] = p;
            }
    }

    __syncthreads();
    if (t < BM) {
#pragma unroll
        for (int r = 0; r < NR; ++r)
            out[(b0 + t) * NR + r] =
                Red[t][r][0] + Red[t][r][1] + Red[t][r][2] + Red[t][r][3];
    }
}

extern "C" void kernel_launch(void* const* d_in, const int* in_sizes, int n_in,
                              void* d_out, int out_size, void* d_ws, size_t ws_size,
                              hipStream_t stream) {
    const float* e1  = (const float*)d_in[0];
    const float* e2  = (const float*)d_in[1];
    const float* rel = (const float*)d_in[2];
    const float* ws  = (const float*)d_in[3];
    float* out = (float*)d_out;
    unsigned short* S_T = (unsigned short*)d_ws;  // NR*ED*ED bf16 = 640 KB

    prep_S<<<(ED * ED + 255) / 256, 256, 0, stream>>>(rel, ws, S_T);

    int B = in_sizes[0] / ED;          // 131072
    int grid = B / BM;                 // 2048
    bilinear_kernel<<<grid, 512, 0, stream>>>(e1, e2, S_T, out);
}

// Round 4
// 249.760 us; speedup vs baseline: 2.0965x; 1.8248x over previous
//
#include <hip/hip_runtime.h>
#include <hip/hip_bf16.h>

#define ED 256   // embed dim
#define NW 8     // num weights
#define NR 5     // num relations
#define BM 128   // rows per block
#define BK 32    // k-chunk staged per step

typedef float  f32x4  __attribute__((ext_vector_type(4)));
typedef __bf16 bf16x8 __attribute__((ext_vector_type(8)));
typedef unsigned short u16;

__device__ __forceinline__ u16 f2bf(float f) {
    return __builtin_bit_cast(u16, __float2bfloat16(f));
}

__device__ __forceinline__ bf16x8 pack8(f32x4 a, f32x4 b) {
    union { u16 u[8]; bf16x8 v; } r;
    r.u[0] = f2bf(a[0]); r.u[1] = f2bf(a[1]); r.u[2] = f2bf(a[2]); r.u[3] = f2bf(a[3]);
    r.u[4] = f2bf(b[0]); r.u[5] = f2bf(b[1]); r.u[6] = f2bf(b[2]); r.u[7] = f2bf(b[3]);
    return r.v;
}

// ---------------------------------------------------------------------------
// Prep: S_T[r][j][i] = sum_w ws[w,r] * rel[w, i*ED + j]   (bf16, [col][k])
// ---------------------------------------------------------------------------
__global__ void prep_S(const float* __restrict__ rel,
                       const float* __restrict__ ws,
                       u16* __restrict__ S_T) {
    int idx = blockIdx.x * blockDim.x + threadIdx.x;
    if (idx >= ED * ED) return;
    int i = idx & (ED - 1);
    int j = idx >> 8;
    float acc[NR];
#pragma unroll
    for (int r = 0; r < NR; ++r) acc[r] = 0.f;
#pragma unroll
    for (int w = 0; w < NW; ++w) {
        float rv = rel[(size_t)w * ED * ED + (size_t)i * ED + j];
#pragma unroll
        for (int r = 0; r < NR; ++r) acc[r] += rv * ws[w * NR + r];
    }
#pragma unroll
    for (int r = 0; r < NR; ++r)
        S_T[((size_t)r * ED + j) * ED + i] = f2bf(acc[r]);
}

// ---------------------------------------------------------------------------
// Main: 512 thr = 8 waves, BM=128 rows. Wave (wr,wc): rows wr*64..+64,
// cols wc*64..+64. A-operand (e1 rows, full K=256) lives in 128 VGPRs,
// reused across all 5 r's. B (S_T) double-buffered in LDS via
// global_load_lds, one __syncthreads per BK=32 step (2-phase pipeline).
// Epilogue: dot with e2 (LDS bf16) + 16-lane shfl reduce -> Red -> out.
// ---------------------------------------------------------------------------
__global__ __launch_bounds__(512, 2) void bilinear_kernel(
    const float* __restrict__ e1, const float* __restrict__ e2,
    const u16* __restrict__ S_T, float* __restrict__ out) {

    __shared__ __align__(16) u16  Bbuf[2][ED * BK];   // 2 x 16 KB
    __shared__ __align__(16) u16  E2l[BM * ED];       // 64 KB bf16
    __shared__ float Red[NR][BM][4];                  // 10 KB

    const int t    = threadIdx.x;
    const int wave = t >> 6;
    const int lane = t & 63;
    const int l15  = lane & 15;
    const int l4   = lane >> 4;
    const int wr   = wave >> 2;    // row group (64 rows)
    const int wc   = wave & 3;     // col slab (64 cols)
    const long b0  = (long)blockIdx.x * BM;

    // ---- issue stage of chunk s=0 (r=0, kb=0) into Bbuf[0] ----
#pragma unroll
    for (int q = 0; q < 2; ++q) {
        int idx = q * 512 + t;                 // 1024 x 16B slots
        int j   = idx >> 2;
        int io  = (idx & 3) * 8;
        const u16* g = S_T + ((size_t)j << 8) + io;
        u16* l = &Bbuf[0][(size_t)(q * 512 + wave * 64) * 8];
        __builtin_amdgcn_global_load_lds(
            (const __attribute__((address_space(1))) unsigned int*)g,
            (__attribute__((address_space(3))) unsigned int*)l, 16, 0, 0);
    }

    // ---- stage e2 tile (f32 -> bf16) into E2l (nontemporal reads) ----
#pragma unroll
    for (int q = 0; q < 16; ++q) {
        int idx = q * 512 + t;                 // float4 idx, BM*ED/4 = 8192
        int row = idx >> 6;
        int c4  = idx & 63;
        f32x4 v = __builtin_nontemporal_load(
            (const f32x4*)(e2 + (b0 + row) * ED + c4 * 4));
        ushort4 p = make_ushort4(f2bf(v[0]), f2bf(v[1]), f2bf(v[2]), f2bf(v[3]));
        *(ushort4*)&E2l[row * ED + c4 * 4] = p;
    }

    // ---- load A-operand into registers: rows wr*64+m*16+l15, all K ----
    bf16x8 av[4][8];                           // 128 VGPRs, reused for all r
#pragma unroll
    for (int m = 0; m < 4; ++m) {
        const float* rowp = e1 + (b0 + wr * 64 + m * 16 + l15) * ED + l4 * 8;
#pragma unroll
        for (int kb = 0; kb < 8; ++kb) {
            f32x4 a = *(const f32x4*)(rowp + kb * 32);
            f32x4 b = *(const f32x4*)(rowp + kb * 32 + 4);
            av[m][kb] = pack8(a, b);
        }
    }

    __syncthreads();   // drains e2 LDS writes AND the s=0 global_load_lds

    for (int r = 0; r < NR; ++r) {
        f32x4 acc[4][4];
#pragma unroll
        for (int m = 0; m < 4; ++m)
#pragma unroll
            for (int n = 0; n < 4; ++n)
                acc[m][n] = f32x4{0.f, 0.f, 0.f, 0.f};

#pragma unroll
        for (int kb = 0; kb < 8; ++kb) {
            const int cur = kb & 1;            // (r*8+kb)&1 == kb&1

            // stage next chunk into the other buffer
            if (kb < 7 || r < NR - 1) {
                const int rn = (kb == 7) ? r + 1 : r;
                const int kn = (kb + 1) & 7;
                const u16* gb = S_T + (size_t)rn * ED * ED + kn * BK;
#pragma unroll
                for (int q = 0; q < 2; ++q) {
                    int idx = q * 512 + t;
                    int j   = idx >> 2;
                    int io  = (idx & 3) * 8;
                    const u16* g = gb + (size_t)j * ED + io;
                    u16* l = &Bbuf[cur ^ 1][(size_t)(q * 512 + wave * 64) * 8];
                    __builtin_amdgcn_global_load_lds(
                        (const __attribute__((address_space(1))) unsigned int*)g,
                        (__attribute__((address_space(3))) unsigned int*)l, 16, 0, 0);
                }
            }

            // B fragments from current buffer (bank-quad perfect, no swizzle)
            bf16x8 bv[4];
#pragma unroll
            for (int n = 0; n < 4; ++n)
                bv[n] = *(const bf16x8*)
                    &Bbuf[cur][(wc * 64 + n * 16 + l15) * BK + l4 * 8];

#pragma unroll
            for (int m = 0; m < 4; ++m)
#pragma unroll
                for (int n = 0; n < 4; ++n)
                    acc[m][n] = __builtin_amdgcn_mfma_f32_16x16x32_bf16(
                        av[m][kb], bv[n], acc[m][n], 0, 0, 0);

            __syncthreads();   // stage(s+1) landed; reads of Bbuf[cur] done
        }

        // ---- epilogue r: dot with e2, 16-lane reduce, stash partials ----
        // C frag: row = wr*64 + m*16 + l4*4 + reg, col = wc*64 + n*16 + l15
#pragma unroll
        for (int m = 0; m < 4; ++m)
#pragma unroll
            for (int reg = 0; reg < 4; ++reg) {
                const int row = wr * 64 + m * 16 + l4 * 4 + reg;
                float p = 0.f;
#pragma unroll
                for (int n = 0; n < 4; ++n) {
                    unsigned bits = (unsigned)E2l[row * ED + wc * 64 + n * 16 + l15] << 16;
                    p += acc[m][n][reg] * __builtin_bit_cast(float, bits);
                }
#pragma unroll
                for (int off = 1; off < 16; off <<= 1)
                    p += __shfl_xor(p, off);
                if (l15 == 0) Red[r][row][wc] = p;
            }
    }

    __syncthreads();
    for (int idx = t; idx < BM * NR; idx += 512) {
        int row = idx / NR;
        int r   = idx - row * NR;
        out[(b0 + row) * NR + r] =
            Red[r][row][0] + Red[r][row][1] + Red[r][row][2] + Red[r][row][3];
    }
}

extern "C" void kernel_launch(void* const* d_in, const int* in_sizes, int n_in,
                              void* d_out, int out_size, void* d_ws, size_t ws_size,
                              hipStream_t stream) {
    const float* e1  = (const float*)d_in[0];
    const float* e2  = (const float*)d_in[1];
    const float* rel = (const float*)d_in[2];
    const float* ws  = (const float*)d_in[3];
    float* out = (float*)d_out;
    u16* S_T = (u16*)d_ws;                     // NR*ED*ED bf16 = 640 KB

    prep_S<<<(ED * ED + 255) / 256, 256, 0, stream>>>(rel, ws, S_T);

    int B = in_sizes[0] / ED;                  // 131072
    int grid = B / BM;                         // 1024
    bilinear_kernel<<<grid, 512, 0, stream>>>(e1, e2, S_T, out);
}

// Round 5
// 243.984 us; speedup vs baseline: 2.1462x; 1.0237x over previous
//
#include <hip/hip_runtime.h>
#include <hip/hip_bf16.h>

#define ED   256   // embed dim
#define NW   8     // num weights
#define NR   5     // num relations
#define BM   64    // rows per block
#define BCOL 128   // cols per block (column half)
#define BK   64    // k per stage step  -> 4 steps per r, 20 total

typedef float  f32x4  __attribute__((ext_vector_type(4)));
typedef __bf16 bf16x8 __attribute__((ext_vector_type(8)));
typedef unsigned short u16;

__device__ __forceinline__ u16 f2bf(float f) {
    return __builtin_bit_cast(u16, __float2bfloat16(f));
}

__device__ __forceinline__ bf16x8 pack8(f32x4 a, f32x4 b) {
    union { u16 u[8]; bf16x8 v; } r;
    r.u[0] = f2bf(a[0]); r.u[1] = f2bf(a[1]); r.u[2] = f2bf(a[2]); r.u[3] = f2bf(a[3]);
    r.u[4] = f2bf(b[0]); r.u[5] = f2bf(b[1]); r.u[6] = f2bf(b[2]); r.u[7] = f2bf(b[3]);
    return r.v;
}

// ---------------------------------------------------------------------------
// Prep: S_T[r][j][i] = sum_w ws[w,r] * rel[w, i*ED + j]   (bf16, [col][k])
// ---------------------------------------------------------------------------
__global__ void prep_S(const float* __restrict__ rel,
                       const float* __restrict__ ws,
                       u16* __restrict__ S_T) {
    int idx = blockIdx.x * blockDim.x + threadIdx.x;
    if (idx >= ED * ED) return;
    int i = idx & (ED - 1);
    int j = idx >> 8;
    float acc[NR];
#pragma unroll
    for (int r = 0; r < NR; ++r) acc[r] = 0.f;
#pragma unroll
    for (int w = 0; w < NW; ++w) {
        float rv = rel[(size_t)w * ED * ED + (size_t)i * ED + j];
#pragma unroll
        for (int r = 0; r < NR; ++r) acc[r] += rv * ws[w * NR + r];
    }
#pragma unroll
    for (int r = 0; r < NR; ++r)
        S_T[((size_t)r * ED + j) * ED + i] = f2bf(acc[r]);
}

// ---------------------------------------------------------------------------
// Main: 256 thr = 4 waves. Block (bx,ch): rows bx*64..+64, cols ch*128..+128.
// Wave (wr,wc): 32 rows x 64 cols. A (e1, full K) in 64 VGPRs, reused over r.
// B chunk [128 cols x 64 k] double-buffered via global_load_lds with XOR
// swizzle (pre-swizzled global source, swizzled ds_read). e2 in 16 VGPRs.
// Col-halves atomicAdd into memset-zeroed out. XCD-paired block decode.
// ---------------------------------------------------------------------------
__global__ __launch_bounds__(256, 3) void bilinear_kernel(
    const float* __restrict__ e1, const float* __restrict__ e2,
    const u16* __restrict__ S_T, float* __restrict__ out) {

    __shared__ __align__(16) u16 Bbuf[2][BCOL * BK];   // 2 x 16 KB
    __shared__ float Red[NR][BM][2];                   // 2.5 KB

    const int t    = threadIdx.x;
    const int wave = t >> 6;
    const int lane = t & 63;
    const int l15  = lane & 15;
    const int l4   = lane >> 4;
    const int wr   = wave >> 1;    // row group (32 rows)
    const int wc   = wave & 1;     // col slab (64 cols within the 128)

    // XCD pairing: blocks (bx,0),(bx,1) adjacent on the same XCD L2.
    const int g       = blockIdx.x;
    const int per_xcd = gridDim.x >> 3;
    const int wgid    = (g & 7) * per_xcd + (g >> 3);
    const int ch      = wgid & 1;
    const long b0     = (long)(wgid >> 1) * BM;

    // ---- staging: step (rr,kb) -> Bbuf[b]; LDS linear, global pre-swizzled
    auto STAGE = [&](int rr, int kb, int b) {
        const u16* gb = S_T + ((size_t)rr * ED + ch * BCOL) * ED + kb * BK;
#pragma unroll
        for (int q = 0; q < 4; ++q) {
            int s  = q * 256 + t;        // 1024 slots x 16B
            int j  = s >> 3;             // col 0..127
            int c  = s & 7;              // physical 16B chunk
            int cl = c ^ (j & 7);        // logical chunk (inverse swizzle)
            const u16* gp = gb + (size_t)j * ED + cl * 8;
            u16* lp = &Bbuf[b][(size_t)(q * 256 + wave * 64) * 8]; // wave-uniform
            __builtin_amdgcn_global_load_lds(
                (const __attribute__((address_space(1))) unsigned int*)gp,
                (__attribute__((address_space(3))) unsigned int*)lp, 16, 0, 0);
        }
    };

    STAGE(0, 0, 0);   // issue first chunk before the register loads

    // ---- A-operand: e1 rows (full K=256) -> 64 VGPRs, reused for all r ----
    bf16x8 av[2][8];
#pragma unroll
    for (int m = 0; m < 2; ++m) {
        const float* rowp = e1 + (b0 + wr * 32 + m * 16 + l15) * ED + l4 * 8;
#pragma unroll
        for (int kb = 0; kb < 8; ++kb) {
            f32x4 a = *(const f32x4*)(rowp + kb * 32);
            f32x4 b = *(const f32x4*)(rowp + kb * 32 + 4);
            av[m][kb] = pack8(a, b);
        }
    }

    // ---- e2 (r-invariant) -> 16 packed VGPRs ----
    // e2p[m][reg][h] packs cols {ch*128 + wc*64 + (2h)*16 + l15, ... (2h+1)*16 + l15}
    unsigned e2p[2][4][2];
#pragma unroll
    for (int m = 0; m < 2; ++m)
#pragma unroll
        for (int reg = 0; reg < 4; ++reg) {
            const float* erow =
                e2 + (b0 + wr * 32 + m * 16 + l4 * 4 + reg) * ED
                   + ch * BCOL + wc * 64 + l15;
#pragma unroll
            for (int h = 0; h < 2; ++h) {
                float a = __builtin_nontemporal_load(erow + (2 * h) * 16);
                float b = __builtin_nontemporal_load(erow + (2 * h + 1) * 16);
                e2p[m][reg][h] = (unsigned)f2bf(a) | ((unsigned)f2bf(b) << 16);
            }
        }

    __syncthreads();   // drains s=0 stage

    for (int r = 0; r < NR; ++r) {
        f32x4 acc[2][4];
#pragma unroll
        for (int m = 0; m < 2; ++m)
#pragma unroll
            for (int n = 0; n < 4; ++n)
                acc[m][n] = f32x4{0.f, 0.f, 0.f, 0.f};

#pragma unroll
        for (int kb = 0; kb < 4; ++kb) {
            const int s   = r * 4 + kb;
            const int cur = s & 1;

            if (s + 1 < NR * 4) {
                const int rn = (kb == 3) ? r + 1 : r;
                const int kn = (kb + 1) & 3;
                STAGE(rn, kn, cur ^ 1);
            }

            // two k-halves of the 64-wide chunk
#pragma unroll
            for (int h = 0; h < 2; ++h) {
                bf16x8 bv[4];
#pragma unroll
                for (int n = 0; n < 4; ++n) {
                    int j  = wc * 64 + n * 16 + l15;           // local col
                    int lb = j * (BK * 2) + h * 64 + l4 * 16;  // logical byte
                    int pb = lb ^ ((j & 7) << 4);              // physical byte
                    bv[n] = *(const bf16x8*)((const char*)Bbuf[cur] + pb);
                }
#pragma unroll
                for (int m = 0; m < 2; ++m)
#pragma unroll
                    for (int n = 0; n < 4; ++n)
                        acc[m][n] = __builtin_amdgcn_mfma_f32_16x16x32_bf16(
                            av[m][kb * 2 + h], bv[n], acc[m][n], 0, 0, 0);
            }

            __syncthreads();   // next chunk landed; reads of Bbuf[cur] done
        }

        // ---- epilogue r: dot with e2 regs, 16-lane reduce, stash ----
        // C frag: row = wr*32 + m*16 + l4*4 + reg, col = wc*64 + n*16 + l15
#pragma unroll
        for (int m = 0; m < 2; ++m)
#pragma unroll
            for (int reg = 0; reg < 4; ++reg) {
                const int row = wr * 32 + m * 16 + l4 * 4 + reg;
                float p = 0.f;
#pragma unroll
                for (int n = 0; n < 4; ++n) {
                    unsigned u = e2p[m][reg][n >> 1];
                    unsigned bits = (n & 1) ? (u & 0xffff0000u) : (u << 16);
                    p += acc[m][n][reg] * __builtin_bit_cast(float, bits);
                }
#pragma unroll
                for (int off = 1; off < 16; off <<= 1)
                    p += __shfl_xor(p, off);
                if (l15 == 0) Red[r][row][wc] = p;
            }
    }

    __syncthreads();
    for (int idx = t; idx < BM * NR; idx += 256) {
        int row = idx / NR;
        int r   = idx - row * NR;
        atomicAdd(&out[(b0 + row) * NR + r], Red[r][row][0] + Red[r][row][1]);
    }
}

extern "C" void kernel_launch(void* const* d_in, const int* in_sizes, int n_in,
                              void* d_out, int out_size, void* d_ws, size_t ws_size,
                              hipStream_t stream) {
    const float* e1  = (const float*)d_in[0];
    const float* e2  = (const float*)d_in[1];
    const float* rel = (const float*)d_in[2];
    const float* ws  = (const float*)d_in[3];
    float* out = (float*)d_out;
    u16* S_T = (u16*)d_ws;                     // NR*ED*ED bf16 = 640 KB

    prep_S<<<(ED * ED + 255) / 256, 256, 0, stream>>>(rel, ws, S_T);

    hipMemsetAsync(out, 0, (size_t)out_size * sizeof(float), stream);

    int B = in_sizes[0] / ED;                  // 131072
    int grid = (B / BM) * 2;                   // 4096 (row-tiles x col-halves)
    bilinear_kernel<<<grid, 256, 0, stream>>>(e1, e2, S_T, out);
}

// Round 6
// 198.641 us; speedup vs baseline: 2.6361x; 1.2283x over previous
//
#include <hip/hip_runtime.h>
#include <hip/hip_bf16.h>

#define ED   256   // embed dim
#define NW   8     // num weights
#define NR   5     // num relations
#define BM   64    // rows per block
#define BCOL 128   // cols per block (column half)
#define BK   64    // k per stage step -> 4 steps per r, 20 total
#define NSTEP (NR * 4)

typedef float  f32x4  __attribute__((ext_vector_type(4)));
typedef __bf16 bf16x8 __attribute__((ext_vector_type(8)));
typedef unsigned short u16;

__device__ __forceinline__ u16 f2bf(float f) {
    return __builtin_bit_cast(u16, __float2bfloat16(f));
}

__device__ __forceinline__ bf16x8 pack8(f32x4 a, f32x4 b) {
    union { u16 u[8]; bf16x8 v; } r;
    r.u[0] = f2bf(a[0]); r.u[1] = f2bf(a[1]); r.u[2] = f2bf(a[2]); r.u[3] = f2bf(a[3]);
    r.u[4] = f2bf(b[0]); r.u[5] = f2bf(b[1]); r.u[6] = f2bf(b[2]); r.u[7] = f2bf(b[3]);
    return r.v;
}

// ---------------------------------------------------------------------------
// Prep: S_T[r][j][i] = sum_w ws[w,r] * rel[w, i*ED + j]   (bf16, [col][k])
// ---------------------------------------------------------------------------
__global__ void prep_S(const float* __restrict__ rel,
                       const float* __restrict__ ws,
                       u16* __restrict__ S_T) {
    int idx = blockIdx.x * blockDim.x + threadIdx.x;
    if (idx >= ED * ED) return;
    int i = idx & (ED - 1);
    int j = idx >> 8;
    float acc[NR];
#pragma unroll
    for (int r = 0; r < NR; ++r) acc[r] = 0.f;
#pragma unroll
    for (int w = 0; w < NW; ++w) {
        float rv = rel[(size_t)w * ED * ED + (size_t)i * ED + j];
#pragma unroll
        for (int r = 0; r < NR; ++r) acc[r] += rv * ws[w * NR + r];
    }
#pragma unroll
    for (int r = 0; r < NR; ++r)
        S_T[((size_t)r * ED + j) * ED + i] = f2bf(acc[r]);
}

// ---------------------------------------------------------------------------
// Main: 256 thr = 4 waves. Block (bx,ch): rows bx*64..+64, cols ch*128..+128.
// A (e1, full K) in 64 VGPRs reused over r; e2 in 16 packed VGPRs.
// B (S_T) staged through a 4-buffer LDS ring via global_load_lds with XOR
// swizzle. T3/T4 schedule: stage chunk s+2 while computing chunk s; counted
// s_waitcnt vmcnt (8 steady / 4 / 0 tail) + raw s_barrier per step — loads
// stay in flight across barriers (never drain to 0 mid-loop).
// ---------------------------------------------------------------------------
__global__ __launch_bounds__(256, 2) void bilinear_kernel(
    const float* __restrict__ e1, const float* __restrict__ e2,
    const u16* __restrict__ S_T, float* __restrict__ out) {

    __shared__ __align__(16) u16 Bbuf[4][BCOL * BK];   // 4 x 16 KB ring
    __shared__ float Red[NR][BM][2];                   // 2.5 KB

    const int t    = threadIdx.x;
    const int wave = t >> 6;
    const int lane = t & 63;
    const int l15  = lane & 15;
    const int l4   = lane >> 4;
    const int wr   = wave >> 1;    // row group (32 rows)
    const int wc   = wave & 1;     // col slab (64 cols within the 128)

    // XCD pairing: blocks (bx,0),(bx,1) adjacent on the same XCD L2.
    const int g       = blockIdx.x;
    const int per_xcd = gridDim.x >> 3;
    const int wgid    = (g & 7) * per_xcd + (g >> 3);
    const int ch      = wgid & 1;
    const long b0     = (long)(wgid >> 1) * BM;

    // staging: chunk (rr,kb) -> ring buffer b. LDS linear, global pre-swizzled
    auto STAGE = [&](int rr, int kb, int b) {
        const u16* gb = S_T + ((size_t)rr * ED + ch * BCOL) * ED + kb * BK;
#pragma unroll
        for (int q = 0; q < 4; ++q) {
            int s  = q * 256 + t;        // 1024 slots x 16B
            int j  = s >> 3;             // col 0..127
            int c  = s & 7;              // physical 16B chunk
            int cl = c ^ (j & 7);        // logical chunk (inverse swizzle)
            const u16* gp = gb + (size_t)j * ED + cl * 8;
            u16* lp = &Bbuf[b][(size_t)(q * 256 + wave * 64) * 8]; // wave-uniform
            __builtin_amdgcn_global_load_lds(
                (const __attribute__((address_space(1))) unsigned int*)gp,
                (__attribute__((address_space(3))) unsigned int*)lp, 16, 0, 0);
        }
    };

    STAGE(0, 0, 0);   // chunk 0
    STAGE(0, 1, 1);   // chunk 1

    // ---- A-operand: e1 rows (full K=256) -> 64 VGPRs, reused for all r ----
    bf16x8 av[2][8];
#pragma unroll
    for (int m = 0; m < 2; ++m) {
        const float* rowp = e1 + (b0 + wr * 32 + m * 16 + l15) * ED + l4 * 8;
#pragma unroll
        for (int kb = 0; kb < 8; ++kb) {
            f32x4 a = *(const f32x4*)(rowp + kb * 32);
            f32x4 b = *(const f32x4*)(rowp + kb * 32 + 4);
            av[m][kb] = pack8(a, b);
        }
    }

    // ---- e2 (r-invariant) -> 16 packed VGPRs ----
    unsigned e2p[2][4][2];
#pragma unroll
    for (int m = 0; m < 2; ++m)
#pragma unroll
        for (int reg = 0; reg < 4; ++reg) {
            const float* erow =
                e2 + (b0 + wr * 32 + m * 16 + l4 * 4 + reg) * ED
                   + ch * BCOL + wc * 64 + l15;
#pragma unroll
            for (int h = 0; h < 2; ++h) {
                float a = __builtin_nontemporal_load(erow + (2 * h) * 16);
                float b = __builtin_nontemporal_load(erow + (2 * h + 1) * 16);
                e2p[m][reg][h] = (unsigned)f2bf(a) | ((unsigned)f2bf(b) << 16);
            }
        }

    // clean vmcnt bookkeeping: prologue loads (incl. chunks 0,1) all land here
    asm volatile("s_waitcnt vmcnt(0)" ::: "memory");
    __builtin_amdgcn_s_barrier();

#pragma unroll
    for (int r = 0; r < NR; ++r) {
        f32x4 acc[2][4];
#pragma unroll
        for (int m = 0; m < 2; ++m)
#pragma unroll
            for (int n = 0; n < 4; ++n)
                acc[m][n] = f32x4{0.f, 0.f, 0.f, 0.f};

#pragma unroll
        for (int kb = 0; kb < 4; ++kb) {
            const int s = r * 4 + kb;            // static after unroll

            // stage chunk s+2 into ring slot (s+2)&3 (overwrites chunk s-2,
            // whose reads all completed before barrier(s-1))
            if (s + 2 < NSTEP) {
                const int sn = s + 2;
                STAGE(sn >> 2, sn & 3, sn & 3);
            }

            // counted wait: chunk s landed when <= (chunks s+1,s+2) in flight
            if (s < NSTEP - 2)
                asm volatile("s_waitcnt vmcnt(8)" ::: "memory");
            else if (s == NSTEP - 2)
                asm volatile("s_waitcnt vmcnt(4)" ::: "memory");
            else
                asm volatile("s_waitcnt vmcnt(0)" ::: "memory");
            __builtin_amdgcn_s_barrier();
            __builtin_amdgcn_sched_barrier(0);

            // two k-halves of the 64-wide chunk
#pragma unroll
            for (int h = 0; h < 2; ++h) {
                bf16x8 bv[4];
#pragma unroll
                for (int n = 0; n < 4; ++n) {
                    int j  = wc * 64 + n * 16 + l15;           // local col
                    int lb = j * (BK * 2) + h * 64 + l4 * 16;  // logical byte
                    int pb = lb ^ ((j & 7) << 4);              // physical byte
                    bv[n] = *(const bf16x8*)((const char*)Bbuf[s & 3] + pb);
                }
#pragma unroll
                for (int m = 0; m < 2; ++m)
#pragma unroll
                    for (int n = 0; n < 4; ++n)
                        acc[m][n] = __builtin_amdgcn_mfma_f32_16x16x32_bf16(
                            av[m][kb * 2 + h], bv[n], acc[m][n], 0, 0, 0);
            }
        }

        // ---- epilogue r: dot with e2 regs, 16-lane reduce, stash ----
#pragma unroll
        for (int m = 0; m < 2; ++m)
#pragma unroll
            for (int reg = 0; reg < 4; ++reg) {
                const int row = wr * 32 + m * 16 + l4 * 4 + reg;
                float p = 0.f;
#pragma unroll
                for (int n = 0; n < 4; ++n) {
                    unsigned u = e2p[m][reg][n >> 1];
                    unsigned bits = (n & 1) ? (u & 0xffff0000u) : (u << 16);
                    p += acc[m][n][reg] * __builtin_bit_cast(float, bits);
                }
#pragma unroll
                for (int off = 1; off < 16; off <<= 1)
                    p += __shfl_xor(p, off);
                if (l15 == 0) Red[r][row][wc] = p;
            }
    }

    __syncthreads();
    for (int idx = t; idx < BM * NR; idx += 256) {
        int row = idx / NR;
        int r   = idx - row * NR;
        atomicAdd(&out[(b0 + row) * NR + r], Red[r][row][0] + Red[r][row][1]);
    }
}

extern "C" void kernel_launch(void* const* d_in, const int* in_sizes, int n_in,
                              void* d_out, int out_size, void* d_ws, size_t ws_size,
                              hipStream_t stream) {
    const float* e1  = (const float*)d_in[0];
    const float* e2  = (const float*)d_in[1];
    const float* rel = (const float*)d_in[2];
    const float* ws  = (const float*)d_in[3];
    float* out = (float*)d_out;
    u16* S_T = (u16*)d_ws;                     // NR*ED*ED bf16 = 640 KB

    prep_S<<<(ED * ED + 255) / 256, 256, 0, stream>>>(rel, ws, S_T);

    hipMemsetAsync(out, 0, (size_t)out_size * sizeof(float), stream);

    int B = in_sizes[0] / ED;                  // 131072
    int grid = (B / BM) * 2;                   // 4096 (row-tiles x col-halves)
    bilinear_kernel<<<grid, 256, 0, stream>>>(e1, e2, S_T, out);
}